// Round 8
// baseline (265.903 us; speedup 1.0000x reference)
//
#include <hip/hip_runtime.h>

#define NTH 512

typedef __attribute__((ext_vector_type(8))) short short8;
typedef __attribute__((ext_vector_type(4))) float floatx4;

// ---- bf16 helpers ----
__device__ __forceinline__ short f2bf(float f) {            // RN-even
    unsigned u = __float_as_uint(f);
    u += 0x7FFF + ((u >> 16) & 1);
    return (short)(u >> 16);
}
__device__ __forceinline__ short f2bf_trunc(float f) {      // truncate (lo plane)
    return (short)(__float_as_uint(f) >> 16);
}
__device__ __forceinline__ float bf2f(short s) {
    return __uint_as_float(((unsigned)(unsigned short)s) << 16);
}

__device__ __forceinline__ float fast_sigmoid(float x) {
    return __builtin_amdgcn_rcpf(1.f + __expf(-x));
}
__device__ __forceinline__ float fast_tanh(float x) {
    return fmaf(-2.f, __builtin_amdgcn_rcpf(__expf(2.f * x) + 1.f), 1.f);
}

// MFMA with B operand pinned to AGPR (gfx950 allows A/B from AGPR, ISA §10).
// D/C tied in VGPRs so the gate math reads acc with no cross-file moves.
__device__ __forceinline__ void mfma_bA(floatx4& d, const short8& a, const short8& b) {
    asm("v_mfma_f32_16x16x32_bf16 %0, %1, %2, %0" : "+v"(d) : "v"(a), "a"(b));
}

// DPP add stage; 0x140,0x141,0x4E,0xB1 together = 16-lane sum broadcast
template<int CTRL>
__device__ __forceinline__ float dpp_add(float v) {
    int o = __builtin_amdgcn_update_dpp(0, __float_as_int(v), CTRL, 0xF, 0xF, true);
    return v + __int_as_float(o);
}

// ---------------------------------------------------------------------------
// Encoder layer: [32,128] (LDS) @ W[128,128] + bias -> [32,128] (LDS)
// ---------------------------------------------------------------------------
template<bool RELU>
__device__ __forceinline__ void mlp_layer(const float (*in)[132],
                                          const float* __restrict__ W,
                                          const float* __restrict__ bias,
                                          float (*outl)[132], int c, int g) {
    float acc[8];
    #pragma unroll
    for (int i = 0; i < 8; i++) acc[i] = 0.f;
    for (int k = 0; k < 128; k += 4) {
        float w0 = W[(k + 0) * 128 + c];
        float w1 = W[(k + 1) * 128 + c];
        float w2 = W[(k + 2) * 128 + c];
        float w3 = W[(k + 3) * 128 + c];
        #pragma unroll
        for (int i = 0; i < 8; i++) {
            const float4 xv = *(const float4*)&in[g * 8 + i][k];
            acc[i] = fmaf(xv.x, w0, fmaf(xv.y, w1, fmaf(xv.z, w2, fmaf(xv.w, w3, acc[i]))));
        }
    }
    const float bv = bias[c];
    #pragma unroll
    for (int i = 0; i < 8; i++) {
        float v = acc[i] + bv;
        outl[g * 8 + i][c] = RELU ? fmaxf(v, 0.f) : v;
    }
}

// ---------------------------------------------------------------------------
// Fused encoder + 50-iter GRU (bf16x3 MFMA, AGPR-resident weights) + per-wave
// decoder (DPP reduce). 32 rows/block, 8 waves; wave w owns gate cols
// {g*128 + w*16 + l15}. One barrier per step.
// ---------------------------------------------------------------------------
__global__ __launch_bounds__(NTH, 1) __attribute__((amdgpu_waves_per_eu(2)))
void gru_fused_kernel(const float* __restrict__ x,
                      const float* __restrict__ ew0, const float* __restrict__ eb0,
                      const float* __restrict__ ew1, const float* __restrict__ eb1,
                      const float* __restrict__ ew2, const float* __restrict__ eb2,
                      const float* __restrict__ w_ih, const float* __restrict__ w_hh,
                      const float* __restrict__ b_ih, const float* __restrict__ b_hh,
                      const float* __restrict__ dw0, const float* __restrict__ db0,
                      const float* __restrict__ dw1, const float* __restrict__ db1,
                      float* __restrict__ out) {
    __shared__ float hA[32][132];                    // encoder staging
    __shared__ float smemB[32 * 132];                // encoder ping buffer
    __shared__ __align__(16) short h_hi[2][32][136]; // bf16 hi planes (dbuf)
    __shared__ __align__(16) short h_lo[2][32][136]; // bf16 lo planes (dbuf)
    __shared__ float outb[32][52];

    const int tid  = threadIdx.x;
    const int b0   = blockIdx.x * 32;
    const int lane = tid & 63;
    const int w    = tid >> 6;     // wave 0..7
    const int quad = lane >> 4;
    const int l15  = lane & 15;
    const int jcol = w * 16 + l15; // this lane's hidden col (per gate)

    // ---------------- encoder: x -> hA ----------------
    {
        const int c = tid & 127;
        const int g = tid >> 7;    // 0..3, 8 rows each
        float acc[8];
        #pragma unroll
        for (int i = 0; i < 8; i++) acc[i] = 0.f;
        for (int k = 0; k < 256; k += 4) {
            float w0 = ew0[(k + 0) * 128 + c];
            float w1 = ew0[(k + 1) * 128 + c];
            float w2 = ew0[(k + 2) * 128 + c];
            float w3 = ew0[(k + 3) * 128 + c];
            #pragma unroll
            for (int i = 0; i < 8; i++) {
                const float4 xv = *(const float4*)(x + (size_t)(b0 + g * 8 + i) * 256 + k);
                acc[i] = fmaf(xv.x, w0, fmaf(xv.y, w1, fmaf(xv.z, w2, fmaf(xv.w, w3, acc[i]))));
            }
        }
        float bv = eb0[c];
        #pragma unroll
        for (int i = 0; i < 8; i++) hA[g * 8 + i][c] = fmaxf(acc[i] + bv, 0.f);
        __syncthreads();
        mlp_layer<true>(hA, ew1, eb1, (float(*)[132])smemB, c, g);
        __syncthreads();
        mlp_layer<false>((float(*)[132])smemB, ew2, eb2, hA, c, g);
        __syncthreads();
    }

    // ---------------- persistent register weights (target: AGPR) ----------
    short8 wbh[3][4], wbl[3][4];
    #pragma unroll
    for (int g = 0; g < 3; g++) {
        const float* wrow = w_hh + (g * 128 + jcol) * 128;
        #pragma unroll
        for (int kt = 0; kt < 4; kt++) {
            const int kb = kt * 32 + quad * 8;
            const float4 f0 = *(const float4*)(wrow + kb);
            const float4 f1 = *(const float4*)(wrow + kb + 4);
            float fv[8] = {f0.x, f0.y, f0.z, f0.w, f1.x, f1.y, f1.z, f1.w};
            short8 hi, lo;
            #pragma unroll
            for (int e = 0; e < 8; e++) {
                short h = f2bf(fv[e]);
                hi[e] = h;
                lo[e] = f2bf_trunc(fv[e] - bf2f(h));
            }
            wbh[g][kt] = hi;
            wbl[g][kt] = lo;
        }
    }
    short8 dwh[4], dwl[4];
    #pragma unroll
    for (int kt = 0; kt < 4; kt++) {
        short8 hi, lo;
        #pragma unroll
        for (int e = 0; e < 8; e++) {
            float f = dw0[(kt * 32 + quad * 8 + e) * 16 + l15];
            short h = f2bf(f);
            hi[e] = h;
            lo[e] = f2bf_trunc(f - bf2f(h));
        }
        dwh[kt] = hi;
        dwl[kt] = lo;
    }
    // gate constants: folded biases for r,z; split for n
    float wihc0 = w_ih[jcol],       bs_r  = b_ih[jcol] + b_hh[jcol];
    float wihc1 = w_ih[128 + jcol], bs_z  = b_ih[128 + jcol] + b_hh[128 + jcol];
    float wihc2 = w_ih[256 + jcol], bih_n = b_ih[256 + jcol], bhh_n = b_hh[256 + jcol];
    const float db0r = db0[l15];
    const float dw1r = dw1[l15];
    const float db1r = db1[0];

    // ---------------- init planes[0] + lane-private fp32 h ----------------
    for (int i = tid; i < 32 * 128; i += NTH) {
        const int b = i >> 7, j = i & 127;
        const float f = hA[b][j];
        const short h = f2bf(f);
        h_hi[0][b][j] = h;
        h_lo[0][b][j] = f2bf_trunc(f - bf2f(h));
    }
    if (tid < 32) outb[tid][0] = 0.f;
    float hold[8];
    #pragma unroll
    for (int mt = 0; mt < 2; mt++)
        #pragma unroll
        for (int reg = 0; reg < 4; reg++)
            hold[mt * 4 + reg] = hA[mt * 16 + quad * 4 + reg][jcol];
    __syncthreads();

    // ---------------- 50 iterations: dec(h_t) -> out[t]; gates -> h_{t+1} ---
    for (int t = 0; t <= 49; t++) {
        const int cur = t & 1, nxt = cur ^ 1;

        // double-buffered per-kt A-frags: [buf][mt], 32 regs total
        short8 ah[2][2], al[2][2];
        {
            const int kb = quad * 8;
            ah[0][0] = *(const short8*)&h_hi[cur][l15][kb];
            al[0][0] = *(const short8*)&h_lo[cur][l15][kb];
            ah[0][1] = *(const short8*)&h_hi[cur][16 + l15][kb];
            al[0][1] = *(const short8*)&h_lo[cur][16 + l15][kb];
        }

        floatx4 acc[2][3];
        #pragma unroll
        for (int mt = 0; mt < 2; mt++)
            #pragma unroll
            for (int g = 0; g < 3; g++) acc[mt][g] = (floatx4){0.f, 0.f, 0.f, 0.f};
        floatx4 dacc[2];
        dacc[0] = (floatx4){0.f, 0.f, 0.f, 0.f};
        dacc[1] = (floatx4){0.f, 0.f, 0.f, 0.f};

        #pragma unroll
        for (int kt = 0; kt < 4; kt++) {
            const int buf = kt & 1;
            if (kt < 3) {   // prefetch kt+1
                const int kb = (kt + 1) * 32 + quad * 8;
                ah[buf ^ 1][0] = *(const short8*)&h_hi[cur][l15][kb];
                al[buf ^ 1][0] = *(const short8*)&h_lo[cur][l15][kb];
                ah[buf ^ 1][1] = *(const short8*)&h_hi[cur][16 + l15][kb];
                al[buf ^ 1][1] = *(const short8*)&h_lo[cur][16 + l15][kb];
            }
            // decoder (2-pass)
            mfma_bA(dacc[0], ah[buf][0], dwh[kt]);
            mfma_bA(dacc[0], ah[buf][0], dwl[kt]);
            mfma_bA(dacc[1], ah[buf][1], dwh[kt]);
            mfma_bA(dacc[1], ah[buf][1], dwl[kt]);
            // GRU (3-pass)
            #pragma unroll
            for (int g = 0; g < 3; g++) {
                mfma_bA(acc[0][g], ah[buf][0], wbh[g][kt]);
                mfma_bA(acc[0][g], ah[buf][0], wbl[g][kt]);
                mfma_bA(acc[0][g], al[buf][0], wbh[g][kt]);
                mfma_bA(acc[1][g], ah[buf][1], wbh[g][kt]);
                mfma_bA(acc[1][g], ah[buf][1], wbl[g][kt]);
                mfma_bA(acc[1][g], al[buf][1], wbh[g][kt]);
            }
        }

        // decoder reduce via DPP (16-lane sum, broadcast)
        float xp[8];
        #pragma unroll
        for (int mt = 0; mt < 2; mt++)
            #pragma unroll
            for (int reg = 0; reg < 4; reg++) {
                float v = fmaxf(dacc[mt][reg] + db0r, 0.f) * dw1r;
                v = dpp_add<0x140>(v);   // row_mirror
                v = dpp_add<0x141>(v);   // row_half_mirror
                v = dpp_add<0x4E>(v);    // quad_perm xor2
                v = dpp_add<0xB1>(v);    // quad_perm xor1
                xp[mt * 4 + reg] = (t == 0) ? 0.f : (v + db1r);
            }
        if (t > 0 && w == 0 && l15 == 0) {
            #pragma unroll
            for (int mt = 0; mt < 2; mt++)
                #pragma unroll
                for (int reg = 0; reg < 4; reg++)
                    outb[mt * 16 + quad * 4 + reg][t] = xp[mt * 4 + reg];
        }

        // gates -> h_{t+1} into planes[nxt]
        if (t < 49) {
            #pragma unroll
            for (int mt = 0; mt < 2; mt++) {
                #pragma unroll
                for (int reg = 0; reg < 4; reg++) {
                    const int b = mt * 16 + quad * 4 + reg;
                    const float xpv = xp[mt * 4 + reg];
                    float gr  = fmaf(xpv, wihc0, acc[mt][0][reg] + bs_r);
                    float gz  = fmaf(xpv, wihc1, acc[mt][1][reg] + bs_z);
                    float ghn = acc[mt][2][reg] + bhh_n;
                    float gxn = fmaf(xpv, wihc2, bih_n);
                    float rg = fast_sigmoid(gr);
                    float zg = fast_sigmoid(gz);
                    float ng = fast_tanh(fmaf(rg, ghn, gxn));
                    const float hn = fmaf(zg, hold[mt * 4 + reg] - ng, ng);
                    hold[mt * 4 + reg] = hn;
                    const short hs = f2bf(hn);
                    h_hi[nxt][b][jcol] = hs;
                    h_lo[nxt][b][jcol] = f2bf_trunc(hn - bf2f(hs));
                }
            }
        }
        __syncthreads();   // planes[nxt] complete; outb[t] visible
    }

    // coalesced output write: [32 rows][50 cols], col 0 = 0
    for (int e = tid; e < 32 * 50; e += NTH) {
        const int b = e / 50;
        const int t = e - b * 50;
        out[(size_t)b0 * 50 + e] = outb[b][t];
    }
}

// ---------------------------------------------------------------------------
extern "C" void kernel_launch(void* const* d_in, const int* in_sizes, int n_in,
                              void* d_out, int out_size, void* d_ws, size_t ws_size,
                              hipStream_t stream) {
    const float* x   = (const float*)d_in[0];
    const float* ew0 = (const float*)d_in[1];
    const float* eb0 = (const float*)d_in[2];
    const float* ew1 = (const float*)d_in[3];
    const float* eb1 = (const float*)d_in[4];
    const float* ew2 = (const float*)d_in[5];
    const float* eb2 = (const float*)d_in[6];
    const float* wih = (const float*)d_in[7];
    const float* whh = (const float*)d_in[8];
    const float* bih = (const float*)d_in[9];
    const float* bhh = (const float*)d_in[10];
    const float* dw0 = (const float*)d_in[11];
    const float* db0 = (const float*)d_in[12];
    const float* dw1 = (const float*)d_in[13];
    const float* db1 = (const float*)d_in[14];
    float* out = (float*)d_out;

    gru_fused_kernel<<<256, NTH, 0, stream>>>(
        x, ew0, eb0, ew1, eb1, ew2, eb2, wih, whh, bih, bhh,
        dw0, db0, dw1, db1, out);
}

// Round 9
// 249.267 us; speedup vs baseline: 1.0667x; 1.0667x over previous
//
#include <hip/hip_runtime.h>

#define NTH 512

typedef __attribute__((ext_vector_type(8))) short short8;
typedef __attribute__((ext_vector_type(4))) float floatx4;

// ---- bf16 helpers ----
__device__ __forceinline__ short f2bf(float f) {            // RN-even (setup only)
    unsigned u = __float_as_uint(f);
    u += 0x7FFF + ((u >> 16) & 1);
    return (short)(u >> 16);
}
__device__ __forceinline__ short f2bf_trunc(float f) {      // truncate (hot loop)
    return (short)(__float_as_uint(f) >> 16);
}
__device__ __forceinline__ float bf2f(short s) {
    return __uint_as_float(((unsigned)(unsigned short)s) << 16);
}
__device__ __forceinline__ float bf_hi_f(float f) {         // trunc-to-bf16 as float
    return __uint_as_float(__float_as_uint(f) & 0xFFFF0000u);
}

__device__ __forceinline__ float fast_sigmoid(float x) {
    return __builtin_amdgcn_rcpf(1.f + __expf(-x));
}
__device__ __forceinline__ float fast_tanh(float x) {
    return fmaf(-2.f, __builtin_amdgcn_rcpf(__expf(2.f * x) + 1.f), 1.f);
}

// DPP add stage; 0x140,0x141,0x4E,0xB1 together = 16-lane sum broadcast
template<int CTRL>
__device__ __forceinline__ float dpp_add(float v) {
    int o = __builtin_amdgcn_update_dpp(0, __float_as_int(v), CTRL, 0xF, 0xF, true);
    return v + __int_as_float(o);
}

#define MFMA __builtin_amdgcn_mfma_f32_16x16x32_bf16

// ---------------------------------------------------------------------------
// Encoder layer: [32,128] (LDS) @ W[128,128] + bias -> [32,128] (LDS)
// ---------------------------------------------------------------------------
template<bool RELU>
__device__ __forceinline__ void mlp_layer(const float (*in)[132],
                                          const float* __restrict__ W,
                                          const float* __restrict__ bias,
                                          float (*outl)[132], int c, int g) {
    float acc[8];
    #pragma unroll
    for (int i = 0; i < 8; i++) acc[i] = 0.f;
    for (int k = 0; k < 128; k += 4) {
        float w0 = W[(k + 0) * 128 + c];
        float w1 = W[(k + 1) * 128 + c];
        float w2 = W[(k + 2) * 128 + c];
        float w3 = W[(k + 3) * 128 + c];
        #pragma unroll
        for (int i = 0; i < 8; i++) {
            const float4 xv = *(const float4*)&in[g * 8 + i][k];
            acc[i] = fmaf(xv.x, w0, fmaf(xv.y, w1, fmaf(xv.z, w2, fmaf(xv.w, w3, acc[i]))));
        }
    }
    const float bv = bias[c];
    #pragma unroll
    for (int i = 0; i < 8; i++) {
        float v = acc[i] + bv;
        outl[g * 8 + i][c] = RELU ? fmaxf(v, 0.f) : v;
    }
}

// ---------------------------------------------------------------------------
// Fused encoder + 50-iter GRU (bf16x3 MFMA) + per-wave decoder (DPP reduce).
// 32 rows/block, 8 waves; wave w owns gate cols {g*128 + w*16 + l15}.
// One barrier per step. Step body split by mt-half so gate VALU (mt0)
// overlaps the mt1 MFMA drain.
// ---------------------------------------------------------------------------
__global__ __launch_bounds__(NTH, 1) __attribute__((amdgpu_waves_per_eu(2)))
void gru_fused_kernel(const float* __restrict__ x,
                      const float* __restrict__ ew0, const float* __restrict__ eb0,
                      const float* __restrict__ ew1, const float* __restrict__ eb1,
                      const float* __restrict__ ew2, const float* __restrict__ eb2,
                      const float* __restrict__ w_ih, const float* __restrict__ w_hh,
                      const float* __restrict__ b_ih, const float* __restrict__ b_hh,
                      const float* __restrict__ dw0, const float* __restrict__ db0,
                      const float* __restrict__ dw1, const float* __restrict__ db1,
                      float* __restrict__ out) {
    __shared__ float hA[32][132];                    // encoder staging
    __shared__ float smemB[32 * 132];                // encoder ping buffer
    __shared__ __align__(16) short h_hi[2][32][136]; // bf16 hi planes (dbuf)
    __shared__ __align__(16) short h_lo[2][32][136]; // bf16 lo planes (dbuf)
    __shared__ float outb[32][52];

    const int tid  = threadIdx.x;
    const int b0   = blockIdx.x * 32;
    const int lane = tid & 63;
    const int w    = tid >> 6;     // wave 0..7
    const int quad = lane >> 4;
    const int l15  = lane & 15;
    const int jcol = w * 16 + l15; // this lane's hidden col (per gate)

    // ---------------- encoder: x -> hA ----------------
    {
        const int c = tid & 127;
        const int g = tid >> 7;    // 0..3, 8 rows each
        float acc[8];
        #pragma unroll
        for (int i = 0; i < 8; i++) acc[i] = 0.f;
        for (int k = 0; k < 256; k += 4) {
            float w0 = ew0[(k + 0) * 128 + c];
            float w1 = ew0[(k + 1) * 128 + c];
            float w2 = ew0[(k + 2) * 128 + c];
            float w3 = ew0[(k + 3) * 128 + c];
            #pragma unroll
            for (int i = 0; i < 8; i++) {
                const float4 xv = *(const float4*)(x + (size_t)(b0 + g * 8 + i) * 256 + k);
                acc[i] = fmaf(xv.x, w0, fmaf(xv.y, w1, fmaf(xv.z, w2, fmaf(xv.w, w3, acc[i]))));
            }
        }
        float bv = eb0[c];
        #pragma unroll
        for (int i = 0; i < 8; i++) hA[g * 8 + i][c] = fmaxf(acc[i] + bv, 0.f);
        __syncthreads();
        mlp_layer<true>(hA, ew1, eb1, (float(*)[132])smemB, c, g);
        __syncthreads();
        mlp_layer<false>((float(*)[132])smemB, ew2, eb2, hA, c, g);
        __syncthreads();
    }

    // ---------------- persistent register weights ----------------
    short8 wbh[3][4], wbl[3][4];
    #pragma unroll
    for (int g = 0; g < 3; g++) {
        const float* wrow = w_hh + (g * 128 + jcol) * 128;
        #pragma unroll
        for (int kt = 0; kt < 4; kt++) {
            const int kb = kt * 32 + quad * 8;
            const float4 f0 = *(const float4*)(wrow + kb);
            const float4 f1 = *(const float4*)(wrow + kb + 4);
            float fv[8] = {f0.x, f0.y, f0.z, f0.w, f1.x, f1.y, f1.z, f1.w};
            short8 hi, lo;
            #pragma unroll
            for (int e = 0; e < 8; e++) {
                short h = f2bf(fv[e]);
                hi[e] = h;
                lo[e] = f2bf_trunc(fv[e] - bf2f(h));
            }
            wbh[g][kt] = hi;
            wbl[g][kt] = lo;
        }
    }
    short8 dwh[4], dwl[4];
    #pragma unroll
    for (int kt = 0; kt < 4; kt++) {
        short8 hi, lo;
        #pragma unroll
        for (int e = 0; e < 8; e++) {
            float f = dw0[(kt * 32 + quad * 8 + e) * 16 + l15];
            short h = f2bf(f);
            hi[e] = h;
            lo[e] = f2bf_trunc(f - bf2f(h));
        }
        dwh[kt] = hi;
        dwl[kt] = lo;
    }
    // gate constants: folded biases for r,z; split for n
    float wihc0 = w_ih[jcol],       bs_r  = b_ih[jcol] + b_hh[jcol];
    float wihc1 = w_ih[128 + jcol], bs_z  = b_ih[128 + jcol] + b_hh[128 + jcol];
    float wihc2 = w_ih[256 + jcol], bih_n = b_ih[256 + jcol], bhh_n = b_hh[256 + jcol];
    const float db0r = db0[l15];
    const float dw1r = dw1[l15];
    const float db1r = db1[0];

    // ---------------- init planes[0] + lane-private fp32 h ----------------
    for (int i = tid; i < 32 * 128; i += NTH) {
        const int b = i >> 7, j = i & 127;
        const float f = hA[b][j];
        h_hi[0][b][j] = f2bf_trunc(f);
        h_lo[0][b][j] = f2bf_trunc(f - bf_hi_f(f));
    }
    if (tid < 32) outb[tid][0] = 0.f;
    float hold[8];
    #pragma unroll
    for (int mt = 0; mt < 2; mt++)
        #pragma unroll
        for (int reg = 0; reg < 4; reg++)
            hold[mt * 4 + reg] = hA[mt * 16 + quad * 4 + reg][jcol];
    __syncthreads();

    // ---------------- 50 iterations: dec(h_t) -> out[t]; gates -> h_{t+1} ---
    for (int t = 0; t <= 49; t++) {
        const int cur = t & 1, nxt = cur ^ 1;

        // all A-frags upfront (16 b128; one vaddr + imm offsets)
        short8 ah[2][4], al[2][4];
        #pragma unroll
        for (int mt = 0; mt < 2; mt++)
            #pragma unroll
            for (int kt = 0; kt < 4; kt++) {
                const int kb = kt * 32 + quad * 8;
                ah[mt][kt] = *(const short8*)&h_hi[cur][mt * 16 + l15][kb];
                al[mt][kt] = *(const short8*)&h_lo[cur][mt * 16 + l15][kb];
            }

        // decoder MFMAs first (both mt), 2-pass
        floatx4 dacc[2];
        dacc[0] = (floatx4){0.f, 0.f, 0.f, 0.f};
        dacc[1] = (floatx4){0.f, 0.f, 0.f, 0.f};
        #pragma unroll
        for (int kt = 0; kt < 4; kt++) {
            dacc[0] = MFMA(ah[0][kt], dwh[kt], dacc[0], 0, 0, 0);
            dacc[0] = MFMA(ah[0][kt], dwl[kt], dacc[0], 0, 0, 0);
            dacc[1] = MFMA(ah[1][kt], dwh[kt], dacc[1], 0, 0, 0);
            dacc[1] = MFMA(ah[1][kt], dwl[kt], dacc[1], 0, 0, 0);
        }

        // GRU mt0 chains (36 MFMAs)
        floatx4 acc0[3], acc1[3];
        #pragma unroll
        for (int g = 0; g < 3; g++) {
            acc0[g] = (floatx4){0.f, 0.f, 0.f, 0.f};
            acc1[g] = (floatx4){0.f, 0.f, 0.f, 0.f};
        }
        #pragma unroll
        for (int kt = 0; kt < 4; kt++)
            #pragma unroll
            for (int g = 0; g < 3; g++) {
                acc0[g] = MFMA(ah[0][kt], wbh[g][kt], acc0[g], 0, 0, 0);
                acc0[g] = MFMA(ah[0][kt], wbl[g][kt], acc0[g], 0, 0, 0);
                acc0[g] = MFMA(al[0][kt], wbh[g][kt], acc0[g], 0, 0, 0);
            }

        // DPP reduce for mt0 xp while mt1 MFMAs are about to issue
        float xp0[4];
        #pragma unroll
        for (int reg = 0; reg < 4; reg++) {
            float v = fmaxf(dacc[0][reg] + db0r, 0.f) * dw1r;
            v = dpp_add<0x140>(v);
            v = dpp_add<0x141>(v);
            v = dpp_add<0x4E>(v);
            v = dpp_add<0xB1>(v);
            xp0[reg] = (t == 0) ? 0.f : (v + db1r);
        }
        if (t > 0 && w == 0 && l15 == 0) {
            #pragma unroll
            for (int reg = 0; reg < 4; reg++)
                outb[quad * 4 + reg][t] = xp0[reg];
        }

        // GRU mt1 chains (36 MFMAs) — gate VALU for mt0 overlaps their drain
        #pragma unroll
        for (int kt = 0; kt < 4; kt++)
            #pragma unroll
            for (int g = 0; g < 3; g++) {
                acc1[g] = MFMA(ah[1][kt], wbh[g][kt], acc1[g], 0, 0, 0);
                acc1[g] = MFMA(ah[1][kt], wbl[g][kt], acc1[g], 0, 0, 0);
                acc1[g] = MFMA(al[1][kt], wbh[g][kt], acc1[g], 0, 0, 0);
            }

        if (t < 49) {
            // gates mt0 -> planes[nxt]
            #pragma unroll
            for (int reg = 0; reg < 4; reg++) {
                const int b = quad * 4 + reg;
                const float xpv = xp0[reg];
                float gr  = fmaf(xpv, wihc0, acc0[0][reg] + bs_r);
                float gz  = fmaf(xpv, wihc1, acc0[1][reg] + bs_z);
                float ghn = acc0[2][reg] + bhh_n;
                float gxn = fmaf(xpv, wihc2, bih_n);
                float rg = fast_sigmoid(gr);
                float zg = fast_sigmoid(gz);
                float ng = fast_tanh(fmaf(rg, ghn, gxn));
                const float hn = fmaf(zg, hold[reg] - ng, ng);
                hold[reg] = hn;
                h_hi[nxt][b][jcol] = f2bf_trunc(hn);
                h_lo[nxt][b][jcol] = f2bf_trunc(hn - bf_hi_f(hn));
            }
        }

        // DPP reduce for mt1 xp
        float xp1[4];
        #pragma unroll
        for (int reg = 0; reg < 4; reg++) {
            float v = fmaxf(dacc[1][reg] + db0r, 0.f) * dw1r;
            v = dpp_add<0x140>(v);
            v = dpp_add<0x141>(v);
            v = dpp_add<0x4E>(v);
            v = dpp_add<0xB1>(v);
            xp1[reg] = (t == 0) ? 0.f : (v + db1r);
        }
        if (t > 0 && w == 0 && l15 == 0) {
            #pragma unroll
            for (int reg = 0; reg < 4; reg++)
                outb[16 + quad * 4 + reg][t] = xp1[reg];
        }

        if (t < 49) {
            // gates mt1 -> planes[nxt]
            #pragma unroll
            for (int reg = 0; reg < 4; reg++) {
                const int b = 16 + quad * 4 + reg;
                const float xpv = xp1[reg];
                float gr  = fmaf(xpv, wihc0, acc1[0][reg] + bs_r);
                float gz  = fmaf(xpv, wihc1, acc1[1][reg] + bs_z);
                float ghn = acc1[2][reg] + bhh_n;
                float gxn = fmaf(xpv, wihc2, bih_n);
                float rg = fast_sigmoid(gr);
                float zg = fast_sigmoid(gz);
                float ng = fast_tanh(fmaf(rg, ghn, gxn));
                const float hn = fmaf(zg, hold[4 + reg] - ng, ng);
                hold[4 + reg] = hn;
                h_hi[nxt][b][jcol] = f2bf_trunc(hn);
                h_lo[nxt][b][jcol] = f2bf_trunc(hn - bf_hi_f(hn));
            }
        }
        __syncthreads();   // planes[nxt] complete; outb[t] visible
    }

    // coalesced output write: [32 rows][50 cols], col 0 = 0
    for (int e = tid; e < 32 * 50; e += NTH) {
        const int b = e / 50;
        const int t = e - b * 50;
        out[(size_t)b0 * 50 + e] = outb[b][t];
    }
}

// ---------------------------------------------------------------------------
extern "C" void kernel_launch(void* const* d_in, const int* in_sizes, int n_in,
                              void* d_out, int out_size, void* d_ws, size_t ws_size,
                              hipStream_t stream) {
    const float* x   = (const float*)d_in[0];
    const float* ew0 = (const float*)d_in[1];
    const float* eb0 = (const float*)d_in[2];
    const float* ew1 = (const float*)d_in[3];
    const float* eb1 = (const float*)d_in[4];
    const float* ew2 = (const float*)d_in[5];
    const float* eb2 = (const float*)d_in[6];
    const float* wih = (const float*)d_in[7];
    const float* whh = (const float*)d_in[8];
    const float* bih = (const float*)d_in[9];
    const float* bhh = (const float*)d_in[10];
    const float* dw0 = (const float*)d_in[11];
    const float* db0 = (const float*)d_in[12];
    const float* dw1 = (const float*)d_in[13];
    const float* db1 = (const float*)d_in[14];
    float* out = (float*)d_out;

    gru_fused_kernel<<<256, NTH, 0, stream>>>(
        x, ew0, eb0, ew1, eb1, ew2, eb2, wih, whh, bih, bhh,
        dw0, db0, dw1, db1, out);
}